// Round 6
// baseline (466.534 us; speedup 1.0000x reference)
//
#include <hip/hip_runtime.h>
#include <math.h>

#define N_NODES 10000
#define E_EDGES 50000
#define NT      40000
#define KS_N    4000
#define ES_E    40000
#define WTOT    400000u   // sum of in-degrees over batched graph (2*E*B), constant
#define CHUNK   16384     // fallback chunk size when ws is small
#define SEL_BLOCKS 40

// ---------- helpers ----------
__device__ __forceinline__ unsigned f2u(float f) {
    unsigned b = __float_as_uint(f);
    return (b & 0x80000000u) ? ~b : (b | 0x80000000u);
}
__device__ __forceinline__ float u2f(unsigned u) {
    unsigned b = (u & 0x80000000u) ? (u & 0x7fffffffu) : ~u;
    return __uint_as_float(b);
}
__device__ __forceinline__ float wave_sum64(float x) {
    for (int off = 32; off > 0; off >>= 1) x += __shfl_down(x, off, 64);
    return x;  // valid on lane 0
}

// ---------- graph build ----------
__global__ void count_deg(const int* __restrict__ ei, unsigned* __restrict__ deg) {
    int j = blockIdx.x * 256 + threadIdx.x;
    if (j < E_EDGES) {
        atomicAdd(&deg[ei[j]], 1u);
        atomicAdd(&deg[ei[E_EDGES + j]], 1u);
    }
}

__global__ __launch_bounds__(1024) void scan_degrees(const unsigned* __restrict__ deg,
                                                     unsigned* __restrict__ rowptr,
                                                     unsigned* __restrict__ cursor) {
    __shared__ unsigned wsum[16];
    __shared__ unsigned carry;
    int tid = threadIdx.x, lane = tid & 63, w = tid >> 6;
    if (tid == 0) carry = 0;
    __syncthreads();
    for (int base = 0; base < N_NODES; base += 1024) {
        int i = base + tid;
        unsigned v = (i < N_NODES) ? deg[i] : 0u;
        unsigned x = v;
        for (int off = 1; off < 64; off <<= 1) {
            unsigned y = __shfl_up(x, off, 64);
            if (lane >= off) x += y;
        }
        if (lane == 63) wsum[w] = x;
        __syncthreads();
        if (tid < 16) {
            unsigned s = wsum[tid];
            for (int off = 1; off < 16; off <<= 1) {
                unsigned y = __shfl_up(s, off, 64);
                if (tid >= off) s += y;
            }
            wsum[tid] = s;
        }
        __syncthreads();
        unsigned woff = (w > 0) ? wsum[w - 1] : 0u;
        unsigned excl = carry + woff + x - v;
        if (i < N_NODES) { rowptr[i] = excl; cursor[i] = excl; }
        __syncthreads();
        if (tid == 0) carry += wsum[15];
        __syncthreads();
    }
    if (tid == 0) rowptr[N_NODES] = carry;
}

__global__ void scatter_edges(const int* __restrict__ ei, const int* __restrict__ ea,
                              unsigned* __restrict__ cursor, unsigned* __restrict__ inedge) {
    int j = blockIdx.x * 256 + threadIdx.x;
    if (j < E_EDGES) {
        unsigned s = (unsigned)ei[j];
        unsigned d = (unsigned)ei[E_EDGES + j];
        unsigned a = (unsigned)ea[j];
        unsigned p1 = atomicAdd(&cursor[d], 1u);
        inedge[p1] = s | (a << 16);
        unsigned p2 = atomicAdd(&cursor[s], 1u);
        inedge[p2] = d | (a << 16);
    }
}

// deterministic single-block pna mean
__global__ __launch_bounds__(1024) void pna_kernel(const unsigned* __restrict__ degb,
                                                   float* __restrict__ scalars) {
    __shared__ float ws[16];
    int tid = threadIdx.x;
    float s = 0.0f;
    for (int i = tid; i < N_NODES; i += 1024) s += logf((float)degb[i] + 1.0f);
    for (int off = 32; off > 0; off >>= 1) s += __shfl_down(s, off, 64);
    if ((tid & 63) == 0) ws[tid >> 6] = s;
    __syncthreads();
    if (tid == 0) {
        float t = 0.0f;
        for (int i = 0; i < 16; ++i) t += ws[i];
        scalars[3] = t / (float)N_NODES;
    }
}

// ---------- init ----------
__global__ void init_hidden(const float* __restrict__ text, float* __restrict__ hidden) {
    int i = blockIdx.x * 256 + threadIdx.x;
    if (i < NT * 64) {
        int v = i >> 6;
        hidden[i] = (v < N_NODES) ? text[i] : 0.0f;
    }
}

__device__ float wave_score_g(float hid, float rel, const float* Wlin, const float* blin,
                              const float* W1, const float* b1, const float* W2, float b2v,
                              int lane) {
    float heur = blin[lane];
    for (int i = 0; i < 64; ++i) heur += __shfl(hid, i, 64) * Wlin[i * 64 + lane];
    for (int i = 0; i < 64; ++i) heur += __shfl(rel, i, 64) * Wlin[(64 + i) * 64 + lane];
    float x = hid * heur;
    float a0 = b1[lane], a1 = b1[64 + lane];
    for (int i = 0; i < 64; ++i) {
        float xv = __shfl(x, i, 64);
        a0 += xv * W1[i * 128 + lane];
        a1 += xv * W1[i * 128 + 64 + lane];
    }
    a0 = fmaxf(a0, 0.0f); a1 = fmaxf(a1, 0.0f);
    float part = a0 * W2[lane] + a1 * W2[64 + lane];
    part = wave_sum64(part);
    part = __shfl(part, 0, 64);
    return part + b2v;
}

__global__ void init_heads(const int* __restrict__ h_index, const int* __restrict__ r_index,
                           const float* __restrict__ hidden_states,
                           const float* __restrict__ rel_table,
                           const float* __restrict__ W_lin, const float* __restrict__ b_lin,
                           const float* __restrict__ W1, const float* __restrict__ b1,
                           const float* __restrict__ W2, const float* __restrict__ b2,
                           float* __restrict__ hidden, float* __restrict__ score,
                           float* __restrict__ qh) {
    __shared__ float q0[64];
    int tid = threadIdx.x, w = tid >> 6, lane = tid & 63;
    int b = w;  // 4 waves, one per batch element
    int h0 = h_index[b * 16] + b * N_NODES;
    float hs  = hidden_states[b * 64 + lane];
    float rel = rel_table[r_index[b * 16] * 64 + lane];
    hidden[h0 * 64 + lane] = hs;
    if (b == 0) q0[lane] = rel;
    float s = wave_score_g(hs, rel, W_lin, b_lin, W1, b1, W2, b2[0], lane);
    if (lane == 0) score[h0] = s;
    __syncthreads();
    if (w == 0) {  // qh[t] = sum_i q0[i]*W_lin[64+i][t] + b_lin[t]
        float acc = b_lin[lane];
        for (int i = 0; i < 64; ++i) acc += q0[i] * W_lin[(64 + i) * 64 + lane];
        qh[lane] = acc;
    }
}

// ---------- fused dual radix select + compact + sigmoid (one kernel per layer) ----------
// 40 blocks; grid spin-barrier via device atomics (all blocks trivially co-resident).
// state: [0]=pn [1]=rn [2]=pw [3]=rw [8]=arrive [9]=release (monotone across layers)
__device__ void block_pick(unsigned h, unsigned r, unsigned* outd, unsigned* outr,
                           unsigned* scr) {
    int tid = threadIdx.x, lane = tid & 63, w = tid >> 6;
    __syncthreads();
    unsigned x = h;
    for (int off = 1; off < 64; off <<= 1) {
        unsigned y = __shfl_up(x, off, 64);
        if (lane >= off) x += y;
    }
    if (lane == 63) scr[w] = x;
    __syncthreads();
    unsigned woff = 0;
    for (int i = 0; i < 4; ++i) if (i < w) woff += scr[i];
    unsigned excl = woff + x - h;
    if (r >= excl && r < excl + h) { scr[4] = (unsigned)tid; scr[5] = r - excl; }
    __syncthreads();
    *outd = scr[4]; *outr = scr[5];
}

__global__ __launch_bounds__(256) void select_compact(
    const float* __restrict__ score, const unsigned* __restrict__ degb,
    unsigned* __restrict__ ghn, unsigned* __restrict__ ghw,
    unsigned* __restrict__ state, float* __restrict__ scalars,
    unsigned* __restrict__ countp, int* __restrict__ list,
    float* __restrict__ sigp, int rbase) {
    __shared__ unsigned lh[512];
    __shared__ unsigned scr[8];
    __shared__ unsigned sh_flag;
    __shared__ unsigned sh_state[4];
    int tid = threadIdx.x;
    unsigned pn = 0, pw = 0;
    unsigned rn = NT - KS_N, rw_ = WTOT - ES_E;
    for (int pass = 0; pass < 4; ++pass) {
        lh[tid] = 0; lh[256 + tid] = 0;
        __syncthreads();
        int shift = 24 - pass * 8;
        for (int v = blockIdx.x * 256 + tid; v < NT; v += SEL_BLOCKS * 256) {
            unsigned key = f2u(score[v]);
            unsigned wg = degb[v % N_NODES];
            unsigned dig = (key >> shift) & 255u;
            if (pass == 0) {
                atomicAdd(&lh[dig], 1u);
                if (wg) atomicAdd(&lh[256 + dig], wg);
            } else {
                unsigned hi = key >> (shift + 8);
                if (hi == pn) atomicAdd(&lh[dig], 1u);
                if (wg && hi == pw) atomicAdd(&lh[256 + dig], wg);
            }
        }
        __syncthreads();
        if (lh[tid]) atomicAdd(&ghn[tid], lh[tid]);
        if (lh[256 + tid]) atomicAdd(&ghw[tid], lh[256 + tid]);
        __threadfence();
        __syncthreads();   // drain all this block's histogram atomics before arriving
        if (tid == 0)
            sh_flag = (atomicAdd(&state[8], 1u) == SEL_BLOCKS - 1) ? 1u : 0u;
        __syncthreads();
        unsigned tgt = (unsigned)(rbase + pass + 1);
        if (sh_flag) {  // last block: pick digits, reset hists, publish
            unsigned hn = atomicAdd(&ghn[tid], 0u);
            unsigned hw = atomicAdd(&ghw[tid], 0u);
            ghn[tid] = 0; ghw[tid] = 0;
            unsigned dn, rn2, dw, rw2;
            block_pick(hn, rn, &dn, &rn2, scr);
            block_pick(hw, rw_, &dw, &rw2, scr);
            if (tid == 0) {
                pn = (pn << 8) | dn;
                pw = (pw << 8) | dw;
                state[0] = pn; state[1] = rn2; state[2] = pw; state[3] = rw2;
                state[8] = 0;
                if (pass == 3) {
                    float thr = u2f(pn), thre = u2f(pw);
                    scalars[0] = thr;
                    scalars[1] = fmaxf(thr, thre);
                    *countp = 0;
                }
                __threadfence();
                atomicExch(&state[9], tgt);   // release
            }
        }
        if (tid == 0) {
            while (atomicAdd(&state[9], 0u) < tgt) __builtin_amdgcn_s_sleep(8);
            sh_state[0] = atomicAdd(&state[0], 0u);
            sh_state[1] = atomicAdd(&state[1], 0u);
            sh_state[2] = atomicAdd(&state[2], 0u);
            sh_state[3] = atomicAdd(&state[3], 0u);
        }
        __syncthreads();
        pn = sh_state[0]; rn = sh_state[1]; pw = sh_state[2]; rw_ = sh_state[3];
    }
    // ---- compact + sigmoid (THR known in-register; countp zeroed by last block) ----
    float thr = u2f(pn);
    float THR = fmaxf(thr, u2f(pw));
    for (int v = blockIdx.x * 256 + tid; v < NT; v += SEL_BLOCKS * 256) {
        float sc = score[v];
        bool ok = sc >= THR;
        float sg = -1.0f;
        if (ok) sg = 1.0f / (1.0f + expf(-sc));
        sigp[v] = sg;
        if (ok && degb[v % N_NODES] > 0) {
            unsigned p = atomicAdd(countp, 1u);
            list[p] = v;
        }
    }
}

// ---------- per-node edge aggregation: one node per wave, no LDS ----------
__global__ __launch_bounds__(256) void agg_feat(
    const float* __restrict__ sigp, const float* __restrict__ hidden,
    const unsigned* __restrict__ rowptr, const unsigned* __restrict__ inedge,
    const float* __restrict__ rel_w, const float* __restrict__ scalars,
    const unsigned* __restrict__ countp, const int* __restrict__ list,
    float* __restrict__ feat, float* __restrict__ ampatt, int layer,
    int mbase, int climit) {
    int count = (int)*countp;
    int cc = count - mbase; if (cc > climit) cc = climit;
    int tid = threadIdx.x, w = tid >> 6, lane = tid & 63;
    int li = blockIdx.x * 4 + w;
    if (li >= cc) return;
    int v = list[mbase + li];
    int b = v / N_NODES;
    int boff = b * N_NODES;
    int n = v - boff;
    const float* rw = rel_w + (size_t)layer * 400 * 64;
    unsigned r0 = rowptr[n], r1 = rowptr[n + 1];
    float sum = 0.f, sq = 0.f, mx = -INFINITY, mn = INFINITY;
    int cnt = 0;
    #pragma unroll 2
    for (unsigned e = r0; e < r1; ++e) {
        unsigned pk = inedge[e];
        int src = (int)(pk & 0xffffu) + boff;
        float sg = sigp[src];
        float h  = hidden[((size_t)src << 6) + lane];
        float rv = rw[((size_t)(pk >> 16) << 6) + lane];
        bool valid = sg >= 0.0f;
        float mval = sg * h * rv;
        if (valid) { sum += mval; sq += mval * mval; }
        mx = fmaxf(mx, valid ? mval : -INFINITY);
        mn = fminf(mn, valid ? mval : INFINITY);
        cnt += valid ? 1 : 0;
    }
    float denom = cnt > 0 ? (float)cnt : 1.0f;
    float mean = sum / denom;
    float sd = sqrtf(fmaxf(sq / denom - mean * mean, 0.0f) + 1e-6f);
    float* fr = feat + ((size_t)li << 8);
    fr[lane]        = mean;
    fr[64 + lane]   = cnt > 0 ? mx : 0.0f;
    fr[128 + lane]  = cnt > 0 ? mn : 0.0f;
    fr[192 + lane]  = sd;
    if (lane == 0) {
        float pna = scalars[3];
        float sl = logf((float)cnt + 1.0f);
        ampatt[li * 2]     = sl / pna;
        ampatt[li * 2 + 1] = pna / (sl + 1e-6f);
    }
}

// ---------- tiled fp32 GEMM: upd[64 x 64] = feat[64 x 256] @ (W0 + amp*W1 + att*W2) ----------
// 4 rows/thread; A-fragment is one ds_read_b128 -> VALU-bound ~2:1.
#define FMA4(C, av, bv) { C[0] += av * bv.x; C[1] += av * bv.y; C[2] += av * bv.z; C[3] += av * bv.w; }

__global__ __launch_bounds__(256) void gemm_upd(
    const float* __restrict__ conv_W, const float* __restrict__ conv_b,
    const unsigned* __restrict__ countp, const float* __restrict__ feat,
    const float* __restrict__ ampatt, float* __restrict__ updc,
    int layer, int mbase, int climit) {
    __shared__ float sA[32][68];     // [kk][row 0..63], pad 68
    __shared__ float sB[32][196];    // [kk][3*64], pad 196
    __shared__ float sAmp[64], sAtt[64];
    int count = (int)*countp;
    int cc = count - mbase; if (cc > climit) cc = climit;
    int m0 = blockIdx.x * 64;
    if (m0 >= cc) return;
    int tid = threadIdx.x;
    if (tid < 64) {
        int rl = m0 + tid;
        float a = 0.f, t = 0.f;
        if (rl < cc) { a = ampatt[rl * 2]; t = ampatt[rl * 2 + 1]; }
        sAmp[tid] = a; sAtt[tid] = t;
    }
    int mg = tid >> 4, ng = tid & 15;   // mg 0..15 -> rows mg*4..mg*4+3
    int j0 = ng * 4;
    float c0[4][4] = {}, c1[4][4] = {}, c2[4][4] = {};
    const float* Wl = conv_W + (size_t)layer * 768 * 64;
    const float4* feat4 = (const float4*)feat;
    for (int k0 = 0; k0 < 256; k0 += 32) {
        __syncthreads();
        #pragma unroll
        for (int it = 0; it < 2; ++it) {   // A tile 64 rows x 32 k, stored [k][m]
            int fi = it * 256 + tid;
            int arow = fi >> 3, akq = fi & 7;
            float4 va = feat4[(((size_t)(m0 + arow)) << 6) + (k0 >> 2) + akq];
            sA[akq * 4 + 0][arow] = va.x; sA[akq * 4 + 1][arow] = va.y;
            sA[akq * 4 + 2][arow] = va.z; sA[akq * 4 + 3][arow] = va.w;
        }
        #pragma unroll
        for (int it = 0; it < 6; ++it) {   // B tile 32 x 192
            int fi = it * 256 + tid;
            int rr = fi >> 4, q = fi & 15;
            int part = rr >> 5, kk = rr & 31;
            float4 vb = *(const float4*)(Wl + (((size_t)(part * 256 + k0 + kk)) << 6) + q * 4);
            float* d = &sB[kk][part * 64 + q * 4];
            d[0] = vb.x; d[1] = vb.y; d[2] = vb.z; d[3] = vb.w;
        }
        __syncthreads();
        #pragma unroll 4
        for (int kk = 0; kk < 32; ++kk) {
            float4 a  = *(const float4*)&sA[kk][mg * 4];
            float4 b0 = *(const float4*)&sB[kk][j0];
            float4 b1 = *(const float4*)&sB[kk][64 + j0];
            float4 b2 = *(const float4*)&sB[kk][128 + j0];
            FMA4(c0[0], a.x, b0) FMA4(c0[1], a.y, b0) FMA4(c0[2], a.z, b0) FMA4(c0[3], a.w, b0)
            FMA4(c1[0], a.x, b1) FMA4(c1[1], a.y, b1) FMA4(c1[2], a.z, b1) FMA4(c1[3], a.w, b1)
            FMA4(c2[0], a.x, b2) FMA4(c2[1], a.y, b2) FMA4(c2[2], a.z, b2) FMA4(c2[3], a.w, b2)
        }
    }
    const float4 bias = *(const float4*)(conv_b + layer * 64 + j0);
    #pragma unroll
    for (int mi = 0; mi < 4; ++mi) {
        int ml = mg * 4 + mi;
        int rl = m0 + ml;
        if (rl < cc) {
            float amp = sAmp[ml], att = sAtt[ml];
            float4 o;
            o.x = fmaxf(c0[mi][0] + amp * c1[mi][0] + att * c2[mi][0] + bias.x, 0.0f);
            o.y = fmaxf(c0[mi][1] + amp * c1[mi][1] + att * c2[mi][1] + bias.y, 0.0f);
            o.z = fmaxf(c0[mi][2] + amp * c1[mi][2] + att * c2[mi][2] + bias.z, 0.0f);
            o.w = fmaxf(c0[mi][3] + amp * c1[mi][3] + att * c2[mi][3] + bias.w, 0.0f);
            *(float4*)(updc + (((size_t)(mbase + rl)) << 6) + j0) = o;
        }
    }
}

// ---------- apply update + score MLP as block-tiled GEMM (64 nodes/block) ----------
// Preserves the exact fp32 accumulation order of the wave-serial version.
__global__ __launch_bounds__(256) void apply_score_gemm(
    float* __restrict__ hidden, const float* __restrict__ updc,
    float* __restrict__ score, const unsigned* __restrict__ countp,
    const int* __restrict__ list,
    const float* __restrict__ W_lin, const float* __restrict__ qh,
    const float* __restrict__ W1, const float* __restrict__ b1,
    const float* __restrict__ W2, const float* __restrict__ b2) {
    __shared__ float sH[64][65];   // h tile; reused as p tile in phase 3
    __shared__ float sX[64][65];   // x = h * heur
    int count = (int)*countp;
    int m0 = blockIdx.x * 64;
    if (m0 >= count) return;
    int tid = threadIdx.x;

    // ---- phase 0: load h, add upd, store back, stage in LDS ----
    {
        int q = tid & 15;
        int mB = tid >> 4;
        #pragma unroll
        for (int r = 0; r < 4; ++r) {
            int m = r * 16 + mB;
            int idx = m0 + m;
            float4 hv = {0.f, 0.f, 0.f, 0.f};
            if (idx < count) {
                int v = list[idx];
                hv = *(const float4*)&hidden[((size_t)v << 6) + q * 4];
                float4 uv = *(const float4*)&updc[((size_t)idx << 6) + q * 4];
                hv.x += uv.x; hv.y += uv.y; hv.z += uv.z; hv.w += uv.w;
                *(float4*)&hidden[((size_t)v << 6) + q * 4] = hv;
            }
            sH[m][q * 4 + 0] = hv.x; sH[m][q * 4 + 1] = hv.y;
            sH[m][q * 4 + 2] = hv.z; sH[m][q * 4 + 3] = hv.w;
        }
    }
    __syncthreads();

    int mg = tid >> 4, ng = tid & 15;
    const float4* Wl4 = (const float4*)W_lin;
    const float4* W14 = (const float4*)W1;
    const float4* qh4 = (const float4*)qh;
    const float4* b14 = (const float4*)b1;
    const float4* W24 = (const float4*)W2;

    // ---- phase 1: heur = H @ Wl + qh ; x = h * heur ----
    {
        float4 qv = qh4[ng];
        float acc[4][4];
        #pragma unroll
        for (int mi = 0; mi < 4; ++mi) {
            acc[mi][0] = qv.x; acc[mi][1] = qv.y; acc[mi][2] = qv.z; acc[mi][3] = qv.w;
        }
        for (int k = 0; k < 64; ++k) {
            float4 bv = Wl4[k * 16 + ng];
            #pragma unroll
            for (int mi = 0; mi < 4; ++mi) {
                float av = sH[mg * 4 + mi][k];
                acc[mi][0] += av * bv.x; acc[mi][1] += av * bv.y;
                acc[mi][2] += av * bv.z; acc[mi][3] += av * bv.w;
            }
        }
        #pragma unroll
        for (int mi = 0; mi < 4; ++mi) {
            int m = mg * 4 + mi;
            #pragma unroll
            for (int ni = 0; ni < 4; ++ni)
                sX[m][ng * 4 + ni] = sH[m][ng * 4 + ni] * acc[mi][ni];
        }
    }
    __syncthreads();

    // ---- phase 2: a = relu(X @ W1 + b1); p = aLo*W2lo + aHi*W2hi ----
    {
        float4 bA = b14[ng], bB = b14[16 + ng];
        float accA[4][4], accB[4][4];
        #pragma unroll
        for (int mi = 0; mi < 4; ++mi) {
            accA[mi][0] = bA.x; accA[mi][1] = bA.y; accA[mi][2] = bA.z; accA[mi][3] = bA.w;
            accB[mi][0] = bB.x; accB[mi][1] = bB.y; accB[mi][2] = bB.z; accB[mi][3] = bB.w;
        }
        for (int k = 0; k < 64; ++k) {
            float4 bvA = W14[k * 32 + ng];
            float4 bvB = W14[k * 32 + 16 + ng];
            #pragma unroll
            for (int mi = 0; mi < 4; ++mi) {
                float av = sX[mg * 4 + mi][k];
                accA[mi][0] += av * bvA.x; accA[mi][1] += av * bvA.y;
                accA[mi][2] += av * bvA.z; accA[mi][3] += av * bvA.w;
                accB[mi][0] += av * bvB.x; accB[mi][1] += av * bvB.y;
                accB[mi][2] += av * bvB.z; accB[mi][3] += av * bvB.w;
            }
        }
        float4 w2A = W24[ng], w2B = W24[16 + ng];
        #pragma unroll
        for (int mi = 0; mi < 4; ++mi) {
            int m = mg * 4 + mi;
            float pA0 = fmaxf(accA[mi][0], 0.f), pB0 = fmaxf(accB[mi][0], 0.f);
            float pA1 = fmaxf(accA[mi][1], 0.f), pB1 = fmaxf(accB[mi][1], 0.f);
            float pA2 = fmaxf(accA[mi][2], 0.f), pB2 = fmaxf(accB[mi][2], 0.f);
            float pA3 = fmaxf(accA[mi][3], 0.f), pB3 = fmaxf(accB[mi][3], 0.f);
            sH[m][ng * 4 + 0] = pA0 * w2A.x + pB0 * w2B.x;
            sH[m][ng * 4 + 1] = pA1 * w2A.y + pB1 * w2B.y;
            sH[m][ng * 4 + 2] = pA2 * w2A.z + pB2 * w2B.z;
            sH[m][ng * 4 + 3] = pA3 * w2A.w + pB3 * w2B.w;
        }
    }
    __syncthreads();

    // ---- phase 3: exact shfl_down tree per row, write score ----
    {
        float b2v = b2[0];
        int w = tid >> 6, lane = tid & 63;
        #pragma unroll 4
        for (int t = 0; t < 16; ++t) {
            int m = w * 16 + t;
            float p = sH[m][lane];
            float s = wave_sum64(p);
            if (lane == 0) {
                int idx = m0 + m;
                if (idx < count) score[list[idx]] = s + b2v;
            }
        }
    }
}

// ---------- output gather ----------
__global__ void gather_out(const float* __restrict__ score, const int* __restrict__ t_index,
                           float* __restrict__ out) {
    int i = threadIdx.x;  // 64 threads
    int b = i >> 4;
    out[i] = score[t_index[i] + b * N_NODES];
}

// ---------- launcher ----------
extern "C" void kernel_launch(void* const* d_in, const int* in_sizes, int n_in,
                              void* d_out, int out_size, void* d_ws, size_t ws_size,
                              hipStream_t stream) {
    const int*   h_index       = (const int*)d_in[0];
    const int*   r_index       = (const int*)d_in[1];
    const int*   t_index       = (const int*)d_in[2];
    const float* hidden_states = (const float*)d_in[3];
    const int*   edge_index    = (const int*)d_in[5];
    const int*   edge_attr     = (const int*)d_in[6];
    const float* text          = (const float*)d_in[7];
    const float* rel_table     = (const float*)d_in[9];
    const float* W_lin         = (const float*)d_in[10];
    const float* b_lin         = (const float*)d_in[11];
    const float* W1            = (const float*)d_in[12];
    const float* b1            = (const float*)d_in[13];
    const float* W2            = (const float*)d_in[14];
    const float* b2            = (const float*)d_in[15];
    const float* rel_w         = (const float*)d_in[16];
    const float* conv_W        = (const float*)d_in[17];
    const float* conv_b        = (const float*)d_in[18];

    // choose full (unchunked) path if scratch allows
    auto layout_bytes = [](size_t fch) -> size_t {
        auto al = [](size_t x) { return (x + 255) & ~(size_t)255; };
        size_t o = 0;
        o += al(256) * 3;                      // scalars, state, countp
        o += al(1024) * 2;                     // ghn, ghw
        o += al((size_t)NT * 4);               // score
        o += al((size_t)N_NODES * 4);          // degb
        o += al(256);                          // qh
        o += al((size_t)NT * 4);               // sigp
        o += al((size_t)NT * 64 * 4);          // hidden
        o += al((size_t)NT * 64 * 4);          // updc
        o += al(fch * 256 * 4);                // feat
        o += al(fch * 2 * 4);                  // ampatt
        o += al((size_t)NT * 4);               // list
        o += al((size_t)(N_NODES + 1) * 4);    // rowptr
        o += al((size_t)N_NODES * 4);          // cursor
        o += al((size_t)2 * E_EDGES * 4);      // inedge
        return o;
    };
    const size_t FCH = (layout_bytes(NT) <= ws_size) ? (size_t)NT : (size_t)CHUNK;
    const int NCH = (FCH == (size_t)NT) ? 1 : 3;

    char* ws = (char*)d_ws;
    size_t off = 0;
    auto carve = [&](size_t bytes) -> char* {
        char* p = ws + off;
        off = (off + bytes + 255) & ~(size_t)255;
        return p;
    };
    // ---- zero-initialized group (contiguous; single memset) ----
    float*    scalars = (float*)carve(256);                 // [0]=thr [1]=THR [3]=pna_mean
    unsigned* state   = (unsigned*)carve(256);              // [0..3]=radix [8]=arrive [9]=release
    unsigned* countp  = (unsigned*)carve(256);
    unsigned* ghn     = (unsigned*)carve(1024);
    unsigned* ghw     = (unsigned*)carve(1024);
    float*    score   = (float*)carve((size_t)NT * 4);
    unsigned* degb    = (unsigned*)carve((size_t)N_NODES * 4);
    size_t zero_end = off;
    // ---- rest ----
    float*    qh      = (float*)carve(256);
    float*    sigp    = (float*)carve((size_t)NT * 4);
    float*    hidden  = (float*)carve((size_t)NT * 64 * 4);
    float*    updc    = (float*)carve((size_t)NT * 64 * 4);
    float*    feat    = (float*)carve(FCH * 256 * 4);
    float*    ampatt  = (float*)carve(FCH * 2 * 4);
    int*      list    = (int*)carve((size_t)NT * 4);
    unsigned* rowptr  = (unsigned*)carve((size_t)(N_NODES + 1) * 4);
    unsigned* cursor  = (unsigned*)carve((size_t)N_NODES * 4);
    unsigned* inedge  = (unsigned*)carve((size_t)2 * E_EDGES * 4);
    if (off > ws_size) return;

    hipMemsetAsync(ws, 0, zero_end, stream);

    count_deg<<<(E_EDGES + 255) / 256, 256, 0, stream>>>(edge_index, degb);
    scan_degrees<<<1, 1024, 0, stream>>>(degb, rowptr, cursor);
    scatter_edges<<<(E_EDGES + 255) / 256, 256, 0, stream>>>(edge_index, edge_attr, cursor, inedge);
    pna_kernel<<<1, 1024, 0, stream>>>(degb, scalars);
    init_hidden<<<(NT * 64 + 255) / 256, 256, 0, stream>>>(text, hidden);
    init_heads<<<1, 256, 0, stream>>>(h_index, r_index, hidden_states, rel_table,
                                      W_lin, b_lin, W1, b1, W2, b2, hidden, score, qh);

    const int climit  = (int)FCH;
    const int aggGrid = climit / 4;
    const int gemGrid = climit / 64;
    for (int l = 0; l < 3; ++l) {
        select_compact<<<SEL_BLOCKS, 256, 0, stream>>>(score, degb, ghn, ghw, state,
                                                       scalars, countp, list, sigp, l * 4);
        for (int c = 0; c < NCH; ++c) {
            int mbase = c * climit;
            agg_feat<<<aggGrid, 256, 0, stream>>>(sigp, hidden, rowptr, inedge, rel_w,
                                                  scalars, countp, list, feat, ampatt,
                                                  l, mbase, climit);
            gemm_upd<<<gemGrid, 256, 0, stream>>>(conv_W, conv_b, countp, feat, ampatt,
                                                  updc, l, mbase, climit);
        }
        apply_score_gemm<<<(NT + 63) / 64, 256, 0, stream>>>(hidden, updc, score, countp,
                                                             list, W_lin, qh, W1, b1, W2, b2);
    }
    gather_out<<<1, 64, 0, stream>>>(score, t_index, (float*)d_out);
}

// Round 7
// 449.460 us; speedup vs baseline: 1.0380x; 1.0380x over previous
//
#include <hip/hip_runtime.h>
#include <math.h>

#define N_NODES 10000
#define E_EDGES 50000
#define NT      40000
#define KS_N    4000
#define ES_E    40000
#define WTOT    400000u   // sum of in-degrees over batched graph (2*E*B), constant
#define CHUNK   16384     // fallback chunk size when ws is small

// ---------- helpers ----------
__device__ __forceinline__ unsigned f2u(float f) {
    unsigned b = __float_as_uint(f);
    return (b & 0x80000000u) ? ~b : (b | 0x80000000u);
}
__device__ __forceinline__ float u2f(unsigned u) {
    unsigned b = (u & 0x80000000u) ? (u & 0x7fffffffu) : ~u;
    return __uint_as_float(b);
}
__device__ __forceinline__ float wave_sum64(float x) {
    for (int off = 32; off > 0; off >>= 1) x += __shfl_down(x, off, 64);
    return x;  // valid on lane 0
}

// ---------- graph build ----------
__global__ void count_deg(const int* __restrict__ ei, unsigned* __restrict__ deg) {
    int j = blockIdx.x * 256 + threadIdx.x;
    if (j < E_EDGES) {
        atomicAdd(&deg[ei[j]], 1u);
        atomicAdd(&deg[ei[E_EDGES + j]], 1u);
    }
}

__global__ __launch_bounds__(1024) void scan_degrees(const unsigned* __restrict__ deg,
                                                     unsigned* __restrict__ rowptr,
                                                     unsigned* __restrict__ cursor) {
    __shared__ unsigned wsum[16];
    __shared__ unsigned carry;
    int tid = threadIdx.x, lane = tid & 63, w = tid >> 6;
    if (tid == 0) carry = 0;
    __syncthreads();
    for (int base = 0; base < N_NODES; base += 1024) {
        int i = base + tid;
        unsigned v = (i < N_NODES) ? deg[i] : 0u;
        unsigned x = v;
        for (int off = 1; off < 64; off <<= 1) {
            unsigned y = __shfl_up(x, off, 64);
            if (lane >= off) x += y;
        }
        if (lane == 63) wsum[w] = x;
        __syncthreads();
        if (tid < 16) {
            unsigned s = wsum[tid];
            for (int off = 1; off < 16; off <<= 1) {
                unsigned y = __shfl_up(s, off, 64);
                if (tid >= off) s += y;
            }
            wsum[tid] = s;
        }
        __syncthreads();
        unsigned woff = (w > 0) ? wsum[w - 1] : 0u;
        unsigned excl = carry + woff + x - v;
        if (i < N_NODES) { rowptr[i] = excl; cursor[i] = excl; }
        __syncthreads();
        if (tid == 0) carry += wsum[15];
        __syncthreads();
    }
    if (tid == 0) rowptr[N_NODES] = carry;
}

__global__ void scatter_edges(const int* __restrict__ ei, const int* __restrict__ ea,
                              unsigned* __restrict__ cursor, unsigned* __restrict__ inedge) {
    int j = blockIdx.x * 256 + threadIdx.x;
    if (j < E_EDGES) {
        unsigned s = (unsigned)ei[j];
        unsigned d = (unsigned)ei[E_EDGES + j];
        unsigned a = (unsigned)ea[j];
        unsigned p1 = atomicAdd(&cursor[d], 1u);
        inedge[p1] = s | (a << 16);
        unsigned p2 = atomicAdd(&cursor[s], 1u);
        inedge[p2] = d | (a << 16);
    }
}

__global__ void tile_degb(const unsigned* __restrict__ degb, unsigned* __restrict__ degbt) {
    int v = blockIdx.x * 256 + threadIdx.x;
    if (v < NT) degbt[v] = degb[v % N_NODES];
}

// deterministic single-block pna mean
__global__ __launch_bounds__(1024) void pna_kernel(const unsigned* __restrict__ degb,
                                                   float* __restrict__ scalars) {
    __shared__ float ws[16];
    int tid = threadIdx.x;
    float s = 0.0f;
    for (int i = tid; i < N_NODES; i += 1024) s += logf((float)degb[i] + 1.0f);
    for (int off = 32; off > 0; off >>= 1) s += __shfl_down(s, off, 64);
    if ((tid & 63) == 0) ws[tid >> 6] = s;
    __syncthreads();
    if (tid == 0) {
        float t = 0.0f;
        for (int i = 0; i < 16; ++i) t += ws[i];
        scalars[3] = t / (float)N_NODES;
    }
}

// ---------- init ----------
__global__ void init_hidden(const float* __restrict__ text, float* __restrict__ hidden) {
    int i = blockIdx.x * 256 + threadIdx.x;
    if (i < NT * 64) {
        int v = i >> 6;
        hidden[i] = (v < N_NODES) ? text[i] : 0.0f;
    }
}

__device__ float wave_score_g(float hid, float rel, const float* Wlin, const float* blin,
                              const float* W1, const float* b1, const float* W2, float b2v,
                              int lane) {
    float heur = blin[lane];
    for (int i = 0; i < 64; ++i) heur += __shfl(hid, i, 64) * Wlin[i * 64 + lane];
    for (int i = 0; i < 64; ++i) heur += __shfl(rel, i, 64) * Wlin[(64 + i) * 64 + lane];
    float x = hid * heur;
    float a0 = b1[lane], a1 = b1[64 + lane];
    for (int i = 0; i < 64; ++i) {
        float xv = __shfl(x, i, 64);
        a0 += xv * W1[i * 128 + lane];
        a1 += xv * W1[i * 128 + 64 + lane];
    }
    a0 = fmaxf(a0, 0.0f); a1 = fmaxf(a1, 0.0f);
    float part = a0 * W2[lane] + a1 * W2[64 + lane];
    part = wave_sum64(part);
    part = __shfl(part, 0, 64);
    return part + b2v;
}

__global__ void init_heads(const int* __restrict__ h_index, const int* __restrict__ r_index,
                           const float* __restrict__ hidden_states,
                           const float* __restrict__ rel_table,
                           const float* __restrict__ W_lin, const float* __restrict__ b_lin,
                           const float* __restrict__ W1, const float* __restrict__ b1,
                           const float* __restrict__ W2, const float* __restrict__ b2,
                           float* __restrict__ hidden, float* __restrict__ score,
                           float* __restrict__ qh) {
    __shared__ float q0[64];
    int tid = threadIdx.x, w = tid >> 6, lane = tid & 63;
    int b = w;  // 4 waves, one per batch element
    int h0 = h_index[b * 16] + b * N_NODES;
    float hs  = hidden_states[b * 64 + lane];
    float rel = rel_table[r_index[b * 16] * 64 + lane];
    hidden[h0 * 64 + lane] = hs;
    if (b == 0) q0[lane] = rel;
    float s = wave_score_g(hs, rel, W_lin, b_lin, W1, b1, W2, b2[0], lane);
    if (lane == 0) score[h0] = s;
    __syncthreads();
    if (w == 0) {  // qh[t] = sum_i q0[i]*W_lin[64+i][t] + b_lin[t]
        float acc = b_lin[lane];
        for (int i = 0; i < 64; ++i) acc += q0[i] * W_lin[(64 + i) * 64 + lane];
        qh[lane] = acc;
    }
}

// ---------- dual radix select, pick folded in via last-block pattern ----------
__device__ void block_pick(unsigned h, unsigned r, unsigned* outd, unsigned* outr,
                           unsigned* scr) {
    // 256 threads; exactly one digit d satisfies excl<=r<excl+h. scr >= 8 words.
    int tid = threadIdx.x, lane = tid & 63, w = tid >> 6;
    __syncthreads();
    unsigned x = h;
    for (int off = 1; off < 64; off <<= 1) {
        unsigned y = __shfl_up(x, off, 64);
        if (lane >= off) x += y;
    }
    if (lane == 63) scr[w] = x;
    __syncthreads();
    unsigned woff = 0;
    for (int i = 0; i < 4; ++i) if (i < w) woff += scr[i];
    unsigned excl = woff + x - h;
    if (r >= excl && r < excl + h) { scr[4] = (unsigned)tid; scr[5] = r - excl; }
    __syncthreads();
    *outd = scr[4]; *outr = scr[5];
}

__global__ __launch_bounds__(256) void select_pass(
    const float* __restrict__ score, const unsigned* __restrict__ degbt,
    unsigned* __restrict__ ghn, unsigned* __restrict__ ghw,
    unsigned* __restrict__ state, float* __restrict__ scalars,
    unsigned* __restrict__ countp, int pass) {
    __shared__ unsigned lh[512];
    __shared__ unsigned scr[8];
    __shared__ unsigned sh_last;
    int tid = threadIdx.x;
    lh[tid] = 0; lh[256 + tid] = 0;
    __syncthreads();
    unsigned pn = state[0], pw = state[2];
    int shift = 24 - pass * 8;
    for (int v = blockIdx.x * 256 + tid; v < NT; v += gridDim.x * 256) {
        unsigned key = f2u(score[v]);
        unsigned wg = degbt[v];
        unsigned dig = (key >> shift) & 255u;
        if (pass == 0) {
            atomicAdd(&lh[dig], 1u);
            if (wg) atomicAdd(&lh[256 + dig], wg);
        } else {
            unsigned hi = key >> (shift + 8);
            if (hi == pn) atomicAdd(&lh[dig], 1u);
            if (wg && hi == pw) atomicAdd(&lh[256 + dig], wg);
        }
    }
    __syncthreads();
    if (lh[tid]) atomicAdd(&ghn[tid], lh[tid]);
    if (lh[256 + tid]) atomicAdd(&ghw[tid], lh[256 + tid]);
    __threadfence();
    if (tid == 0) sh_last = atomicAdd(&state[8 + pass], 1u);
    __syncthreads();
    if (sh_last != gridDim.x - 1) return;
    // ---- last block: pick digit for both selects, reset hists ----
    unsigned hn = atomicAdd(&ghn[tid], 0u);
    unsigned hw = atomicAdd(&ghw[tid], 0u);
    ghn[tid] = 0; ghw[tid] = 0;
    unsigned rn, rw_;
    if (pass == 0) { pn = 0; rn = NT - KS_N; pw = 0; rw_ = WTOT - ES_E; }
    else { rn = state[1]; rw_ = state[3]; }
    unsigned dn, rn2, dw, rw2;
    block_pick(hn, rn, &dn, &rn2, scr);
    block_pick(hw, rw_, &dw, &rw2, scr);
    if (tid == 0) {
        pn = (pn << 8) | dn;
        pw = (pw << 8) | dw;
        state[0] = pn; state[1] = rn2; state[2] = pw; state[3] = rw2;
        state[8 + pass] = 0;  // reset arrival counter for next layer
        if (pass == 3) {
            float thr = u2f(pn), thre = u2f(pw);
            scalars[0] = thr;
            scalars[1] = fmaxf(thr, thre);  // effective edge/node threshold
            *countp = 0;
        }
    }
}

// ---------- compact + sigmoid precompute ----------
__global__ void compact_sig(const float* __restrict__ score, const unsigned* __restrict__ degbt,
                            const float* __restrict__ scalars, unsigned* __restrict__ countp,
                            int* __restrict__ list, float* __restrict__ sigp) {
    int v = blockIdx.x * 256 + threadIdx.x;
    if (v >= NT) return;
    float sc = score[v];
    bool pass = sc >= scalars[1];
    float sg = -1.0f;
    if (pass) sg = 1.0f / (1.0f + expf(-sc));
    sigp[v] = sg;
    if (pass && degbt[v] > 0) {
        unsigned p = atomicAdd(countp, 1u);
        list[p] = v;
    }
}

// ---------- per-node edge aggregation: one node per wave, no LDS ----------
__global__ __launch_bounds__(256) void agg_feat(
    const float* __restrict__ sigp, const float* __restrict__ hidden,
    const unsigned* __restrict__ rowptr, const unsigned* __restrict__ inedge,
    const float* __restrict__ rel_w, const float* __restrict__ scalars,
    const unsigned* __restrict__ countp, const int* __restrict__ list,
    float* __restrict__ feat, float* __restrict__ ampatt, int layer,
    int mbase, int climit) {
    int count = (int)*countp;
    int cc = count - mbase; if (cc > climit) cc = climit;
    int tid = threadIdx.x, w = tid >> 6, lane = tid & 63;
    int li = blockIdx.x * 4 + w;
    if (li >= cc) return;
    int v = list[mbase + li];
    int b = v / N_NODES;
    int boff = b * N_NODES;
    int n = v - boff;
    const float* rw = rel_w + (size_t)layer * 400 * 64;
    unsigned r0 = rowptr[n], r1 = rowptr[n + 1];
    float sum = 0.f, sq = 0.f, mx = -INFINITY, mn = INFINITY;
    int cnt = 0;
    #pragma unroll 2
    for (unsigned e = r0; e < r1; ++e) {
        unsigned pk = inedge[e];
        int src = (int)(pk & 0xffffu) + boff;
        float sg = sigp[src];
        float h  = hidden[((size_t)src << 6) + lane];
        float rv = rw[((size_t)(pk >> 16) << 6) + lane];
        bool valid = sg >= 0.0f;
        float mval = sg * h * rv;
        if (valid) { sum += mval; sq += mval * mval; }
        mx = fmaxf(mx, valid ? mval : -INFINITY);
        mn = fminf(mn, valid ? mval : INFINITY);
        cnt += valid ? 1 : 0;
    }
    float denom = cnt > 0 ? (float)cnt : 1.0f;
    float mean = sum / denom;
    float sd = sqrtf(fmaxf(sq / denom - mean * mean, 0.0f) + 1e-6f);
    float* fr = feat + ((size_t)li << 8);
    fr[lane]        = mean;
    fr[64 + lane]   = cnt > 0 ? mx : 0.0f;
    fr[128 + lane]  = cnt > 0 ? mn : 0.0f;
    fr[192 + lane]  = sd;
    if (lane == 0) {
        float pna = scalars[3];
        float sl = logf((float)cnt + 1.0f);
        ampatt[li * 2]     = sl / pna;
        ampatt[li * 2 + 1] = pna / (sl + 1e-6f);
    }
}

// ---------- tiled fp32 GEMM: upd[64 x 64] = feat[64 x 256] @ (W0 + amp*W1 + att*W2) ----------
// 4 rows/thread. A staged row-major sA[64][36]: float4 writes at bank floor
// (4*(r+akq)%32 covers all starts), scalar reads 2-way (free). FMA order per
// output = k ascending, identical to prior passing versions.
#define FMA4(C, av, bv) { C[0] += av * bv.x; C[1] += av * bv.y; C[2] += av * bv.z; C[3] += av * bv.w; }

__global__ __launch_bounds__(256) void gemm_upd(
    const float* __restrict__ conv_W, const float* __restrict__ conv_b,
    const unsigned* __restrict__ countp, const float* __restrict__ feat,
    const float* __restrict__ ampatt, float* __restrict__ updc,
    int layer, int mbase, int climit) {
    __shared__ float sA[64][36];     // [row][k], stride 144B (16B-aligned rows)
    __shared__ float sB[32][196];    // [kk][3*64]
    __shared__ float sAmp[64], sAtt[64];
    int count = (int)*countp;
    int cc = count - mbase; if (cc > climit) cc = climit;
    int m0 = blockIdx.x * 64;
    if (m0 >= cc) return;
    int tid = threadIdx.x;
    if (tid < 64) {
        int rl = m0 + tid;
        float a = 0.f, t = 0.f;
        if (rl < cc) { a = ampatt[rl * 2]; t = ampatt[rl * 2 + 1]; }
        sAmp[tid] = a; sAtt[tid] = t;
    }
    int mg = tid >> 4, ng = tid & 15;   // mg 0..15 -> rows mg*4..mg*4+3
    int j0 = ng * 4;
    float c0[4][4] = {}, c1[4][4] = {}, c2[4][4] = {};
    const float* Wl = conv_W + (size_t)layer * 768 * 64;
    const float4* feat4 = (const float4*)feat;
    int arow = tid >> 3, akq = tid & 7;  // A staging: 2 iters x (32 rows x 8 kquads)
    for (int k0 = 0; k0 < 256; k0 += 32) {
        __syncthreads();
        #pragma unroll
        for (int it = 0; it < 2; ++it) {   // A tile 64 rows x 32 k, row-major
            int r = it * 32 + arow;
            float4 va = feat4[(((size_t)(m0 + r)) << 6) + (k0 >> 2) + akq];
            *(float4*)&sA[r][akq * 4] = va;
        }
        #pragma unroll
        for (int it = 0; it < 6; ++it) {   // B tile 32 x 192
            int fi = it * 256 + tid;
            int rr = fi >> 4, q = fi & 15;
            int part = rr >> 5, kk = rr & 31;
            float4 vb = *(const float4*)(Wl + (((size_t)(part * 256 + k0 + kk)) << 6) + q * 4);
            float* d = &sB[kk][part * 64 + q * 4];
            d[0] = vb.x; d[1] = vb.y; d[2] = vb.z; d[3] = vb.w;
        }
        __syncthreads();
        #pragma unroll 4
        for (int kk = 0; kk < 32; ++kk) {
            float a0 = sA[mg * 4 + 0][kk];
            float a1 = sA[mg * 4 + 1][kk];
            float a2 = sA[mg * 4 + 2][kk];
            float a3 = sA[mg * 4 + 3][kk];
            float4 b0 = *(const float4*)&sB[kk][j0];
            float4 b1 = *(const float4*)&sB[kk][64 + j0];
            float4 b2 = *(const float4*)&sB[kk][128 + j0];
            FMA4(c0[0], a0, b0) FMA4(c0[1], a1, b0) FMA4(c0[2], a2, b0) FMA4(c0[3], a3, b0)
            FMA4(c1[0], a0, b1) FMA4(c1[1], a1, b1) FMA4(c1[2], a2, b1) FMA4(c1[3], a3, b1)
            FMA4(c2[0], a0, b2) FMA4(c2[1], a1, b2) FMA4(c2[2], a2, b2) FMA4(c2[3], a3, b2)
        }
    }
    const float4 bias = *(const float4*)(conv_b + layer * 64 + j0);
    #pragma unroll
    for (int mi = 0; mi < 4; ++mi) {
        int ml = mg * 4 + mi;
        int rl = m0 + ml;
        if (rl < cc) {
            float amp = sAmp[ml], att = sAtt[ml];
            float4 o;
            o.x = fmaxf(c0[mi][0] + amp * c1[mi][0] + att * c2[mi][0] + bias.x, 0.0f);
            o.y = fmaxf(c0[mi][1] + amp * c1[mi][1] + att * c2[mi][1] + bias.y, 0.0f);
            o.z = fmaxf(c0[mi][2] + amp * c1[mi][2] + att * c2[mi][2] + bias.z, 0.0f);
            o.w = fmaxf(c0[mi][3] + amp * c1[mi][3] + att * c2[mi][3] + bias.w, 0.0f);
            *(float4*)(updc + (((size_t)(mbase + rl)) << 6) + j0) = o;
        }
    }
}

// ---------- apply update + score MLP as block-tiled GEMM (64 nodes/block) ----------
// Preserves the exact fp32 accumulation order of the wave-serial version.
__global__ __launch_bounds__(256) void apply_score_gemm(
    float* __restrict__ hidden, const float* __restrict__ updc,
    float* __restrict__ score, const unsigned* __restrict__ countp,
    const int* __restrict__ list,
    const float* __restrict__ W_lin, const float* __restrict__ qh,
    const float* __restrict__ W1, const float* __restrict__ b1,
    const float* __restrict__ W2, const float* __restrict__ b2) {
    __shared__ float sH[64][65];   // h tile; reused as p tile in phase 3
    __shared__ float sX[64][65];   // x = h * heur
    int count = (int)*countp;
    int m0 = blockIdx.x * 64;
    if (m0 >= count) return;
    int tid = threadIdx.x;

    // ---- phase 0: load h, add upd, store back, stage in LDS ----
    {
        int q = tid & 15;
        int mB = tid >> 4;
        #pragma unroll
        for (int r = 0; r < 4; ++r) {
            int m = r * 16 + mB;
            int idx = m0 + m;
            float4 hv = {0.f, 0.f, 0.f, 0.f};
            if (idx < count) {
                int v = list[idx];
                hv = *(const float4*)&hidden[((size_t)v << 6) + q * 4];
                float4 uv = *(const float4*)&updc[((size_t)idx << 6) + q * 4];
                hv.x += uv.x; hv.y += uv.y; hv.z += uv.z; hv.w += uv.w;
                *(float4*)&hidden[((size_t)v << 6) + q * 4] = hv;
            }
            sH[m][q * 4 + 0] = hv.x; sH[m][q * 4 + 1] = hv.y;
            sH[m][q * 4 + 2] = hv.z; sH[m][q * 4 + 3] = hv.w;
        }
    }
    __syncthreads();

    int mg = tid >> 4, ng = tid & 15;
    const float4* Wl4 = (const float4*)W_lin;
    const float4* W14 = (const float4*)W1;
    const float4* qh4 = (const float4*)qh;
    const float4* b14 = (const float4*)b1;
    const float4* W24 = (const float4*)W2;

    // ---- phase 1: heur = H @ Wl + qh ; x = h * heur ----
    {
        float4 qv = qh4[ng];
        float acc[4][4];
        #pragma unroll
        for (int mi = 0; mi < 4; ++mi) {
            acc[mi][0] = qv.x; acc[mi][1] = qv.y; acc[mi][2] = qv.z; acc[mi][3] = qv.w;
        }
        for (int k = 0; k < 64; ++k) {
            float4 bv = Wl4[k * 16 + ng];
            #pragma unroll
            for (int mi = 0; mi < 4; ++mi) {
                float av = sH[mg * 4 + mi][k];
                acc[mi][0] += av * bv.x; acc[mi][1] += av * bv.y;
                acc[mi][2] += av * bv.z; acc[mi][3] += av * bv.w;
            }
        }
        #pragma unroll
        for (int mi = 0; mi < 4; ++mi) {
            int m = mg * 4 + mi;
            #pragma unroll
            for (int ni = 0; ni < 4; ++ni)
                sX[m][ng * 4 + ni] = sH[m][ng * 4 + ni] * acc[mi][ni];
        }
    }
    __syncthreads();

    // ---- phase 2: a = relu(X @ W1 + b1); p = aLo*W2lo + aHi*W2hi ----
    {
        float4 bA = b14[ng], bB = b14[16 + ng];
        float accA[4][4], accB[4][4];
        #pragma unroll
        for (int mi = 0; mi < 4; ++mi) {
            accA[mi][0] = bA.x; accA[mi][1] = bA.y; accA[mi][2] = bA.z; accA[mi][3] = bA.w;
            accB[mi][0] = bB.x; accB[mi][1] = bB.y; accB[mi][2] = bB.z; accB[mi][3] = bB.w;
        }
        for (int k = 0; k < 64; ++k) {
            float4 bvA = W14[k * 32 + ng];
            float4 bvB = W14[k * 32 + 16 + ng];
            #pragma unroll
            for (int mi = 0; mi < 4; ++mi) {
                float av = sX[mg * 4 + mi][k];
                accA[mi][0] += av * bvA.x; accA[mi][1] += av * bvA.y;
                accA[mi][2] += av * bvA.z; accA[mi][3] += av * bvA.w;
                accB[mi][0] += av * bvB.x; accB[mi][1] += av * bvB.y;
                accB[mi][2] += av * bvB.z; accB[mi][3] += av * bvB.w;
            }
        }
        float4 w2A = W24[ng], w2B = W24[16 + ng];
        #pragma unroll
        for (int mi = 0; mi < 4; ++mi) {
            int m = mg * 4 + mi;
            float pA0 = fmaxf(accA[mi][0], 0.f), pB0 = fmaxf(accB[mi][0], 0.f);
            float pA1 = fmaxf(accA[mi][1], 0.f), pB1 = fmaxf(accB[mi][1], 0.f);
            float pA2 = fmaxf(accA[mi][2], 0.f), pB2 = fmaxf(accB[mi][2], 0.f);
            float pA3 = fmaxf(accA[mi][3], 0.f), pB3 = fmaxf(accB[mi][3], 0.f);
            sH[m][ng * 4 + 0] = pA0 * w2A.x + pB0 * w2B.x;
            sH[m][ng * 4 + 1] = pA1 * w2A.y + pB1 * w2B.y;
            sH[m][ng * 4 + 2] = pA2 * w2A.z + pB2 * w2B.z;
            sH[m][ng * 4 + 3] = pA3 * w2A.w + pB3 * w2B.w;
        }
    }
    __syncthreads();

    // ---- phase 3: exact shfl_down tree per row, write score ----
    {
        float b2v = b2[0];
        int w = tid >> 6, lane = tid & 63;
        #pragma unroll 4
        for (int t = 0; t < 16; ++t) {
            int m = w * 16 + t;
            float p = sH[m][lane];
            float s = wave_sum64(p);
            if (lane == 0) {
                int idx = m0 + m;
                if (idx < count) score[list[idx]] = s + b2v;
            }
        }
    }
}

// ---------- output gather ----------
__global__ void gather_out(const float* __restrict__ score, const int* __restrict__ t_index,
                           float* __restrict__ out) {
    int i = threadIdx.x;  // 64 threads
    int b = i >> 4;
    out[i] = score[t_index[i] + b * N_NODES];
}

// ---------- launcher ----------
extern "C" void kernel_launch(void* const* d_in, const int* in_sizes, int n_in,
                              void* d_out, int out_size, void* d_ws, size_t ws_size,
                              hipStream_t stream) {
    const int*   h_index       = (const int*)d_in[0];
    const int*   r_index       = (const int*)d_in[1];
    const int*   t_index       = (const int*)d_in[2];
    const float* hidden_states = (const float*)d_in[3];
    const int*   edge_index    = (const int*)d_in[5];
    const int*   edge_attr     = (const int*)d_in[6];
    const float* text          = (const float*)d_in[7];
    const float* rel_table     = (const float*)d_in[9];
    const float* W_lin         = (const float*)d_in[10];
    const float* b_lin         = (const float*)d_in[11];
    const float* W1            = (const float*)d_in[12];
    const float* b1            = (const float*)d_in[13];
    const float* W2            = (const float*)d_in[14];
    const float* b2            = (const float*)d_in[15];
    const float* rel_w         = (const float*)d_in[16];
    const float* conv_W        = (const float*)d_in[17];
    const float* conv_b        = (const float*)d_in[18];

    // choose full (unchunked) path if scratch allows
    auto layout_bytes = [](size_t fch) -> size_t {
        auto al = [](size_t x) { return (x + 255) & ~(size_t)255; };
        size_t o = 0;
        o += al(256) * 3;                      // scalars, state, countp
        o += al(1024) * 2;                     // ghn, ghw
        o += al((size_t)NT * 4);               // score
        o += al((size_t)N_NODES * 4);          // degb
        o += al(256);                          // qh
        o += al((size_t)NT * 4);               // sigp
        o += al((size_t)NT * 64 * 4);          // hidden
        o += al((size_t)NT * 64 * 4);          // updc
        o += al(fch * 256 * 4);                // feat
        o += al(fch * 2 * 4);                  // ampatt
        o += al((size_t)NT * 4);               // list
        o += al((size_t)NT * 4);               // degbt
        o += al((size_t)(N_NODES + 1) * 4);    // rowptr
        o += al((size_t)N_NODES * 4);          // cursor
        o += al((size_t)2 * E_EDGES * 4);      // inedge
        return o;
    };
    const size_t FCH = (layout_bytes(NT) <= ws_size) ? (size_t)NT : (size_t)CHUNK;
    const int NCH = (FCH == (size_t)NT) ? 1 : 3;

    char* ws = (char*)d_ws;
    size_t off = 0;
    auto carve = [&](size_t bytes) -> char* {
        char* p = ws + off;
        off = (off + bytes + 255) & ~(size_t)255;
        return p;
    };
    // ---- zero-initialized group (contiguous; single memset) ----
    float*    scalars = (float*)carve(256);                 // [0]=thr [1]=THR [3]=pna_mean
    unsigned* state   = (unsigned*)carve(256);              // [0..3]=radix state [8..11]=arrival
    unsigned* countp  = (unsigned*)carve(256);
    unsigned* ghn     = (unsigned*)carve(1024);
    unsigned* ghw     = (unsigned*)carve(1024);
    float*    score   = (float*)carve((size_t)NT * 4);
    unsigned* degb    = (unsigned*)carve((size_t)N_NODES * 4);
    size_t zero_end = off;
    // ---- rest ----
    float*    qh      = (float*)carve(256);
    float*    sigp    = (float*)carve((size_t)NT * 4);
    float*    hidden  = (float*)carve((size_t)NT * 64 * 4);
    float*    updc    = (float*)carve((size_t)NT * 64 * 4);
    float*    feat    = (float*)carve(FCH * 256 * 4);
    float*    ampatt  = (float*)carve(FCH * 2 * 4);
    int*      list    = (int*)carve((size_t)NT * 4);
    unsigned* degbt   = (unsigned*)carve((size_t)NT * 4);
    unsigned* rowptr  = (unsigned*)carve((size_t)(N_NODES + 1) * 4);
    unsigned* cursor  = (unsigned*)carve((size_t)N_NODES * 4);
    unsigned* inedge  = (unsigned*)carve((size_t)2 * E_EDGES * 4);
    if (off > ws_size) return;

    hipMemsetAsync(ws, 0, zero_end, stream);

    count_deg<<<(E_EDGES + 255) / 256, 256, 0, stream>>>(edge_index, degb);
    scan_degrees<<<1, 1024, 0, stream>>>(degb, rowptr, cursor);
    scatter_edges<<<(E_EDGES + 255) / 256, 256, 0, stream>>>(edge_index, edge_attr, cursor, inedge);
    tile_degb<<<(NT + 255) / 256, 256, 0, stream>>>(degb, degbt);
    pna_kernel<<<1, 1024, 0, stream>>>(degb, scalars);
    init_hidden<<<(NT * 64 + 255) / 256, 256, 0, stream>>>(text, hidden);
    init_heads<<<1, 256, 0, stream>>>(h_index, r_index, hidden_states, rel_table,
                                      W_lin, b_lin, W1, b1, W2, b2, hidden, score, qh);

    const int climit  = (int)FCH;
    const int aggGrid = climit / 4;
    const int gemGrid = climit / 64;
    for (int l = 0; l < 3; ++l) {
        for (int p = 0; p < 4; ++p)
            select_pass<<<40, 256, 0, stream>>>(score, degbt, ghn, ghw, state,
                                                scalars, countp, p);
        compact_sig<<<(NT + 255) / 256, 256, 0, stream>>>(score, degbt, scalars,
                                                          countp, list, sigp);
        for (int c = 0; c < NCH; ++c) {
            int mbase = c * climit;
            agg_feat<<<aggGrid, 256, 0, stream>>>(sigp, hidden, rowptr, inedge, rel_w,
                                                  scalars, countp, list, feat, ampatt,
                                                  l, mbase, climit);
            gemm_upd<<<gemGrid, 256, 0, stream>>>(conv_W, conv_b, countp, feat, ampatt,
                                                  updc, l, mbase, climit);
        }
        apply_score_gemm<<<(NT + 63) / 64, 256, 0, stream>>>(hidden, updc, score, countp,
                                                             list, W_lin, qh, W1, b1, W2, b2);
    }
    gather_out<<<1, 64, 0, stream>>>(score, t_index, (float*)d_out);
}

// Round 8
// 395.856 us; speedup vs baseline: 1.1785x; 1.1354x over previous
//
#include <hip/hip_runtime.h>
#include <math.h>

#define N_NODES 10000
#define E_EDGES 50000
#define NT      40000
#define KS_N    4000
#define ES_E    40000
#define WTOT    400000u   // sum of in-degrees over batched graph (2*E*B), constant
#define CHUNK   16384     // fallback chunk size when ws is small
#define SEL_BLOCKS 40

// ---------- helpers ----------
__device__ __forceinline__ unsigned f2u(float f) {
    unsigned b = __float_as_uint(f);
    return (b & 0x80000000u) ? ~b : (b | 0x80000000u);
}
__device__ __forceinline__ float u2f(unsigned u) {
    unsigned b = (u & 0x80000000u) ? (u & 0x7fffffffu) : ~u;
    return __uint_as_float(b);
}
__device__ __forceinline__ float wave_sum64(float x) {
    for (int off = 32; off > 0; off >>= 1) x += __shfl_down(x, off, 64);
    return x;  // valid on lane 0
}

// ---------- graph build ----------
__global__ void count_deg(const int* __restrict__ ei, unsigned* __restrict__ deg) {
    int j = blockIdx.x * 256 + threadIdx.x;
    if (j < E_EDGES) {
        atomicAdd(&deg[ei[j]], 1u);
        atomicAdd(&deg[ei[E_EDGES + j]], 1u);
    }
}

__global__ __launch_bounds__(1024) void scan_degrees(const unsigned* __restrict__ deg,
                                                     unsigned* __restrict__ rowptr,
                                                     unsigned* __restrict__ cursor) {
    __shared__ unsigned wsum[16];
    __shared__ unsigned carry;
    int tid = threadIdx.x, lane = tid & 63, w = tid >> 6;
    if (tid == 0) carry = 0;
    __syncthreads();
    for (int base = 0; base < N_NODES; base += 1024) {
        int i = base + tid;
        unsigned v = (i < N_NODES) ? deg[i] : 0u;
        unsigned x = v;
        for (int off = 1; off < 64; off <<= 1) {
            unsigned y = __shfl_up(x, off, 64);
            if (lane >= off) x += y;
        }
        if (lane == 63) wsum[w] = x;
        __syncthreads();
        if (tid < 16) {
            unsigned s = wsum[tid];
            for (int off = 1; off < 16; off <<= 1) {
                unsigned y = __shfl_up(s, off, 64);
                if (tid >= off) s += y;
            }
            wsum[tid] = s;
        }
        __syncthreads();
        unsigned woff = (w > 0) ? wsum[w - 1] : 0u;
        unsigned excl = carry + woff + x - v;
        if (i < N_NODES) { rowptr[i] = excl; cursor[i] = excl; }
        __syncthreads();
        if (tid == 0) carry += wsum[15];
        __syncthreads();
    }
    if (tid == 0) rowptr[N_NODES] = carry;
}

__global__ void scatter_edges(const int* __restrict__ ei, const int* __restrict__ ea,
                              unsigned* __restrict__ cursor, unsigned* __restrict__ inedge) {
    int j = blockIdx.x * 256 + threadIdx.x;
    if (j < E_EDGES) {
        unsigned s = (unsigned)ei[j];
        unsigned d = (unsigned)ei[E_EDGES + j];
        unsigned a = (unsigned)ea[j];
        unsigned p1 = atomicAdd(&cursor[d], 1u);
        inedge[p1] = s | (a << 16);
        unsigned p2 = atomicAdd(&cursor[s], 1u);
        inedge[p2] = d | (a << 16);
    }
}

// deterministic single-block pna mean
__global__ __launch_bounds__(1024) void pna_kernel(const unsigned* __restrict__ degb,
                                                   float* __restrict__ scalars) {
    __shared__ float ws[16];
    int tid = threadIdx.x;
    float s = 0.0f;
    for (int i = tid; i < N_NODES; i += 1024) s += logf((float)degb[i] + 1.0f);
    for (int off = 32; off > 0; off >>= 1) s += __shfl_down(s, off, 64);
    if ((tid & 63) == 0) ws[tid >> 6] = s;
    __syncthreads();
    if (tid == 0) {
        float t = 0.0f;
        for (int i = 0; i < 16; ++i) t += ws[i];
        scalars[3] = t / (float)N_NODES;
    }
}

// ---------- init ----------
__global__ void init_hidden(const float* __restrict__ text, float* __restrict__ hidden) {
    int i = blockIdx.x * 256 + threadIdx.x;
    if (i < NT * 64) {
        int v = i >> 6;
        hidden[i] = (v < N_NODES) ? text[i] : 0.0f;
    }
}

__device__ float wave_score_g(float hid, float rel, const float* Wlin, const float* blin,
                              const float* W1, const float* b1, const float* W2, float b2v,
                              int lane) {
    float heur = blin[lane];
    for (int i = 0; i < 64; ++i) heur += __shfl(hid, i, 64) * Wlin[i * 64 + lane];
    for (int i = 0; i < 64; ++i) heur += __shfl(rel, i, 64) * Wlin[(64 + i) * 64 + lane];
    float x = hid * heur;
    float a0 = b1[lane], a1 = b1[64 + lane];
    for (int i = 0; i < 64; ++i) {
        float xv = __shfl(x, i, 64);
        a0 += xv * W1[i * 128 + lane];
        a1 += xv * W1[i * 128 + 64 + lane];
    }
    a0 = fmaxf(a0, 0.0f); a1 = fmaxf(a1, 0.0f);
    float part = a0 * W2[lane] + a1 * W2[64 + lane];
    part = wave_sum64(part);
    part = __shfl(part, 0, 64);
    return part + b2v;
}

__global__ void init_heads(const int* __restrict__ h_index, const int* __restrict__ r_index,
                           const float* __restrict__ hidden_states,
                           const float* __restrict__ rel_table,
                           const float* __restrict__ W_lin, const float* __restrict__ b_lin,
                           const float* __restrict__ W1, const float* __restrict__ b1,
                           const float* __restrict__ W2, const float* __restrict__ b2,
                           float* __restrict__ hidden, float* __restrict__ score,
                           float* __restrict__ qh) {
    __shared__ float q0[64];
    int tid = threadIdx.x, w = tid >> 6, lane = tid & 63;
    int b = w;  // 4 waves, one per batch element
    int h0 = h_index[b * 16] + b * N_NODES;
    float hs  = hidden_states[b * 64 + lane];
    float rel = rel_table[r_index[b * 16] * 64 + lane];
    hidden[h0 * 64 + lane] = hs;
    if (b == 0) q0[lane] = rel;
    float s = wave_score_g(hs, rel, W_lin, b_lin, W1, b1, W2, b2[0], lane);
    if (lane == 0) score[h0] = s;
    __syncthreads();
    if (w == 0) {  // qh[t] = sum_i q0[i]*W_lin[64+i][t] + b_lin[t]
        float acc = b_lin[lane];
        for (int i = 0; i < 64; ++i) acc += q0[i] * W_lin[(64 + i) * 64 + lane];
        qh[lane] = acc;
    }
}

// ---------- fused dual radix select + compact + sigmoid (one kernel per layer) ----------
// 40 blocks; grid spin-barrier via device atomics (all blocks trivially co-resident).
// state: [0]=pn [1]=rn [2]=pw [3]=rw [8]=arrive [9]=release (monotone across layers)
__device__ void block_pick(unsigned h, unsigned r, unsigned* outd, unsigned* outr,
                           unsigned* scr) {
    int tid = threadIdx.x, lane = tid & 63, w = tid >> 6;
    __syncthreads();
    unsigned x = h;
    for (int off = 1; off < 64; off <<= 1) {
        unsigned y = __shfl_up(x, off, 64);
        if (lane >= off) x += y;
    }
    if (lane == 63) scr[w] = x;
    __syncthreads();
    unsigned woff = 0;
    for (int i = 0; i < 4; ++i) if (i < w) woff += scr[i];
    unsigned excl = woff + x - h;
    if (r >= excl && r < excl + h) { scr[4] = (unsigned)tid; scr[5] = r - excl; }
    __syncthreads();
    *outd = scr[4]; *outr = scr[5];
}

__global__ __launch_bounds__(256) void select_compact(
    const float* __restrict__ score, const unsigned* __restrict__ degb,
    unsigned* __restrict__ ghn, unsigned* __restrict__ ghw,
    unsigned* __restrict__ state, float* __restrict__ scalars,
    unsigned* __restrict__ countp, int* __restrict__ list,
    float* __restrict__ sigp, int rbase) {
    __shared__ unsigned lh[512];
    __shared__ unsigned scr[8];
    __shared__ unsigned sh_flag;
    __shared__ unsigned sh_state[4];
    int tid = threadIdx.x;
    unsigned pn = 0, pw = 0;
    unsigned rn = NT - KS_N, rw_ = WTOT - ES_E;
    for (int pass = 0; pass < 4; ++pass) {
        lh[tid] = 0; lh[256 + tid] = 0;
        __syncthreads();
        int shift = 24 - pass * 8;
        for (int v = blockIdx.x * 256 + tid; v < NT; v += SEL_BLOCKS * 256) {
            unsigned key = f2u(score[v]);
            unsigned wg = degb[v % N_NODES];
            unsigned dig = (key >> shift) & 255u;
            if (pass == 0) {
                atomicAdd(&lh[dig], 1u);
                if (wg) atomicAdd(&lh[256 + dig], wg);
            } else {
                unsigned hi = key >> (shift + 8);
                if (hi == pn) atomicAdd(&lh[dig], 1u);
                if (wg && hi == pw) atomicAdd(&lh[256 + dig], wg);
            }
        }
        __syncthreads();
        if (lh[tid]) atomicAdd(&ghn[tid], lh[tid]);
        if (lh[256 + tid]) atomicAdd(&ghw[tid], lh[256 + tid]);
        __threadfence();
        __syncthreads();   // drain this block's histogram atomics before arriving
        if (tid == 0)
            sh_flag = (atomicAdd(&state[8], 1u) == SEL_BLOCKS - 1) ? 1u : 0u;
        __syncthreads();
        unsigned tgt = (unsigned)(rbase + pass + 1);
        if (sh_flag) {  // last block: pick digits, reset hists, publish
            unsigned hn = atomicAdd(&ghn[tid], 0u);
            unsigned hw = atomicAdd(&ghw[tid], 0u);
            ghn[tid] = 0; ghw[tid] = 0;
            unsigned dn, rn2, dw, rw2;
            block_pick(hn, rn, &dn, &rn2, scr);
            block_pick(hw, rw_, &dw, &rw2, scr);
            if (tid == 0) {
                pn = (pn << 8) | dn;
                pw = (pw << 8) | dw;
                state[0] = pn; state[1] = rn2; state[2] = pw; state[3] = rw2;
                state[8] = 0;
                if (pass == 3) {
                    float thr = u2f(pn), thre = u2f(pw);
                    scalars[0] = thr;
                    scalars[1] = fmaxf(thr, thre);
                    *countp = 0;
                }
                __threadfence();
                atomicExch(&state[9], tgt);   // release
            }
        }
        if (tid == 0) {
            while (atomicAdd(&state[9], 0u) < tgt) __builtin_amdgcn_s_sleep(8);
            sh_state[0] = atomicAdd(&state[0], 0u);
            sh_state[1] = atomicAdd(&state[1], 0u);
            sh_state[2] = atomicAdd(&state[2], 0u);
            sh_state[3] = atomicAdd(&state[3], 0u);
        }
        __syncthreads();
        pn = sh_state[0]; rn = sh_state[1]; pw = sh_state[2]; rw_ = sh_state[3];
    }
    // ---- compact + sigmoid (THR known in-register; countp zeroed pre-release) ----
    float thr = u2f(pn);
    float THR = fmaxf(thr, u2f(pw));
    for (int v = blockIdx.x * 256 + tid; v < NT; v += SEL_BLOCKS * 256) {
        float sc = score[v];
        bool ok = sc >= THR;
        float sg = -1.0f;
        if (ok) sg = 1.0f / (1.0f + expf(-sc));
        sigp[v] = sg;
        if (ok && degb[v % N_NODES] > 0) {
            unsigned p = atomicAdd(countp, 1u);
            list[p] = v;
        }
    }
}

// ---------- per-node edge aggregation: one node per wave, no LDS ----------
__global__ __launch_bounds__(256) void agg_feat(
    const float* __restrict__ sigp, const float* __restrict__ hidden,
    const unsigned* __restrict__ rowptr, const unsigned* __restrict__ inedge,
    const float* __restrict__ rel_w, const float* __restrict__ scalars,
    const unsigned* __restrict__ countp, const int* __restrict__ list,
    float* __restrict__ feat, float* __restrict__ ampatt, int layer,
    int mbase, int climit) {
    int count = (int)*countp;
    int cc = count - mbase; if (cc > climit) cc = climit;
    int tid = threadIdx.x, w = tid >> 6, lane = tid & 63;
    int li = blockIdx.x * 4 + w;
    if (li >= cc) return;
    int v = list[mbase + li];
    int b = v / N_NODES;
    int boff = b * N_NODES;
    int n = v - boff;
    const float* rw = rel_w + (size_t)layer * 400 * 64;
    unsigned r0 = rowptr[n], r1 = rowptr[n + 1];
    float sum = 0.f, sq = 0.f, mx = -INFINITY, mn = INFINITY;
    int cnt = 0;
    #pragma unroll 2
    for (unsigned e = r0; e < r1; ++e) {
        unsigned pk = inedge[e];
        int src = (int)(pk & 0xffffu) + boff;
        float sg = sigp[src];
        float h  = hidden[((size_t)src << 6) + lane];
        float rv = rw[((size_t)(pk >> 16) << 6) + lane];
        bool valid = sg >= 0.0f;
        float mval = sg * h * rv;
        if (valid) { sum += mval; sq += mval * mval; }
        mx = fmaxf(mx, valid ? mval : -INFINITY);
        mn = fminf(mn, valid ? mval : INFINITY);
        cnt += valid ? 1 : 0;
    }
    float denom = cnt > 0 ? (float)cnt : 1.0f;
    float mean = sum / denom;
    float sd = sqrtf(fmaxf(sq / denom - mean * mean, 0.0f) + 1e-6f);
    float* fr = feat + ((size_t)li << 8);
    fr[lane]        = mean;
    fr[64 + lane]   = cnt > 0 ? mx : 0.0f;
    fr[128 + lane]  = cnt > 0 ? mn : 0.0f;
    fr[192 + lane]  = sd;
    if (lane == 0) {
        float pna = scalars[3];
        float sl = logf((float)cnt + 1.0f);
        ampatt[li * 2]     = sl / pna;
        ampatt[li * 2 + 1] = pna / (sl + 1e-6f);
    }
}

// ---------- fused: upd GEMM (32 rows/block) + apply + score MLP ----------
// GEMM accumulation (k ascending, FMA4 order) and MLP phases are element-wise
// identical to the previously passing kernels -> bitwise-same scores.
#define FMA4(C, av, bv) { C[0] += av * bv.x; C[1] += av * bv.y; C[2] += av * bv.z; C[3] += av * bv.w; }

__global__ __launch_bounds__(256) void update_score(
    const float* __restrict__ conv_W, const float* __restrict__ conv_b,
    const unsigned* __restrict__ countp, const float* __restrict__ feat,
    const float* __restrict__ ampatt, float* __restrict__ hidden,
    float* __restrict__ score, const int* __restrict__ list,
    const float* __restrict__ W_lin, const float* __restrict__ qh,
    const float* __restrict__ W1, const float* __restrict__ b1,
    const float* __restrict__ W2, const float* __restrict__ b2,
    int layer, int mbase, int climit) {
    // union: gemm view sA[32][34] + sB[32][196]  (7360 floats)
    //        mlp  view sH[32][65] + sX[32][65]   (4160 floats)  -- after barrier
    __shared__ float smem[32 * 34 + 32 * 196 + 64];
    float* sA   = smem;                    // [kk][row], stride 34
    float* sB   = smem + 32 * 34;          // [kk][col], stride 196
    float* sAmp = smem + 32 * 34 + 32 * 196;
    float* sAtt = sAmp + 32;
    int count = (int)*countp;
    int cc = count - mbase; if (cc > climit) cc = climit;
    int m0 = blockIdx.x * 32;
    if (m0 >= cc) return;
    int tid = threadIdx.x;
    if (tid < 32) {
        int rl = m0 + tid;
        float a = 0.f, t = 0.f;
        if (rl < cc) { a = ampatt[rl * 2]; t = ampatt[rl * 2 + 1]; }
        sAmp[tid] = a; sAtt[tid] = t;
    }
    int mg = tid >> 4, ng = tid & 15, j0 = ng * 4;
    float c0[2][4] = {}, c1[2][4] = {}, c2[2][4] = {};
    const float* Wl = conv_W + (size_t)layer * 768 * 64;
    const float4* feat4 = (const float4*)feat;
    int arow = tid >> 3, akq = tid & 7;
    // ---- GEMM: upd[32x64] = feat[32x256] @ (W0 + amp*W1 + att*W2) ----
    for (int k0 = 0; k0 < 256; k0 += 32) {
        __syncthreads();
        {
            float4 va = feat4[(((size_t)(m0 + arow)) << 6) + (k0 >> 2) + akq];
            sA[(akq * 4 + 0) * 34 + arow] = va.x;
            sA[(akq * 4 + 1) * 34 + arow] = va.y;
            sA[(akq * 4 + 2) * 34 + arow] = va.z;
            sA[(akq * 4 + 3) * 34 + arow] = va.w;
        }
        #pragma unroll
        for (int it = 0; it < 6; ++it) {
            int fi = it * 256 + tid;
            int rr = fi >> 4, q = fi & 15;
            int part = rr >> 5, kk = rr & 31;
            float4 vb = *(const float4*)(Wl + (((size_t)(part * 256 + k0 + kk)) << 6) + q * 4);
            float* d = &sB[kk * 196 + part * 64 + q * 4];
            d[0] = vb.x; d[1] = vb.y; d[2] = vb.z; d[3] = vb.w;
        }
        __syncthreads();
        #pragma unroll 4
        for (int kk = 0; kk < 32; ++kk) {
            float a0 = sA[kk * 34 + mg * 2];
            float a1 = sA[kk * 34 + mg * 2 + 1];
            float4 b0 = *(const float4*)&sB[kk * 196 + j0];
            float4 b1v = *(const float4*)&sB[kk * 196 + 64 + j0];
            float4 b2v = *(const float4*)&sB[kk * 196 + 128 + j0];
            FMA4(c0[0], a0, b0)  FMA4(c0[1], a1, b0)
            FMA4(c1[0], a0, b1v) FMA4(c1[1], a1, b1v)
            FMA4(c2[0], a0, b2v) FMA4(c2[1], a1, b2v)
        }
    }
    // epilogue into registers
    const float4 bias = *(const float4*)(conv_b + layer * 64 + j0);
    float4 o[2];
    #pragma unroll
    for (int mi = 0; mi < 2; ++mi) {
        int ml = mg * 2 + mi;
        float amp = sAmp[ml], att = sAtt[ml];
        o[mi].x = fmaxf(c0[mi][0] + amp * c1[mi][0] + att * c2[mi][0] + bias.x, 0.0f);
        o[mi].y = fmaxf(c0[mi][1] + amp * c1[mi][1] + att * c2[mi][1] + bias.y, 0.0f);
        o[mi].z = fmaxf(c0[mi][2] + amp * c1[mi][2] + att * c2[mi][2] + bias.z, 0.0f);
        o[mi].w = fmaxf(c0[mi][3] + amp * c1[mi][3] + att * c2[mi][3] + bias.w, 0.0f);
    }
    __syncthreads();   // all gemm LDS reads complete -> safe to reuse smem
    float* sH = smem;            // [32][65]
    float* sX = smem + 32 * 65;  // [32][65]
    #pragma unroll
    for (int mi = 0; mi < 2; ++mi) {
        int ml = mg * 2 + mi;
        sH[ml * 65 + j0 + 0] = o[mi].x; sH[ml * 65 + j0 + 1] = o[mi].y;
        sH[ml * 65 + j0 + 2] = o[mi].z; sH[ml * 65 + j0 + 3] = o[mi].w;
    }
    __syncthreads();
    // ---- phase 0: h = hidden + upd; write back; stage h ----
    {
        int q = tid & 15, mB = tid >> 4;
        #pragma unroll
        for (int r = 0; r < 2; ++r) {
            int m = r * 16 + mB;
            int idx = m0 + m;
            if (idx < cc) {
                int v = list[mbase + idx];
                float4 hv = *(const float4*)&hidden[((size_t)v << 6) + q * 4];
                float h0 = hv.x + sH[m * 65 + q * 4 + 0];
                float h1 = hv.y + sH[m * 65 + q * 4 + 1];
                float h2 = hv.z + sH[m * 65 + q * 4 + 2];
                float h3 = hv.w + sH[m * 65 + q * 4 + 3];
                float4 hw = {h0, h1, h2, h3};
                *(float4*)&hidden[((size_t)v << 6) + q * 4] = hw;
                sH[m * 65 + q * 4 + 0] = h0; sH[m * 65 + q * 4 + 1] = h1;
                sH[m * 65 + q * 4 + 2] = h2; sH[m * 65 + q * 4 + 3] = h3;
            } else {
                sH[m * 65 + q * 4 + 0] = 0.f; sH[m * 65 + q * 4 + 1] = 0.f;
                sH[m * 65 + q * 4 + 2] = 0.f; sH[m * 65 + q * 4 + 3] = 0.f;
            }
        }
    }
    __syncthreads();
    const float4* Wl4 = (const float4*)W_lin;
    const float4* W14 = (const float4*)W1;
    // ---- phase 1: heur = H @ Wl + qh ; x = h * heur ----
    {
        float4 qv = ((const float4*)qh)[ng];
        float acc[2][4];
        #pragma unroll
        for (int mi = 0; mi < 2; ++mi) {
            acc[mi][0] = qv.x; acc[mi][1] = qv.y; acc[mi][2] = qv.z; acc[mi][3] = qv.w;
        }
        for (int k = 0; k < 64; ++k) {
            float4 bv = Wl4[k * 16 + ng];
            #pragma unroll
            for (int mi = 0; mi < 2; ++mi) {
                float av = sH[(mg * 2 + mi) * 65 + k];
                acc[mi][0] += av * bv.x; acc[mi][1] += av * bv.y;
                acc[mi][2] += av * bv.z; acc[mi][3] += av * bv.w;
            }
        }
        #pragma unroll
        for (int mi = 0; mi < 2; ++mi) {
            int m = mg * 2 + mi;
            #pragma unroll
            for (int ni = 0; ni < 4; ++ni)
                sX[m * 65 + j0 + ni] = sH[m * 65 + j0 + ni] * acc[mi][ni];
        }
    }
    __syncthreads();
    // ---- phase 2: a = relu(X @ W1 + b1); p = aLo*W2lo + aHi*W2hi ----
    {
        float4 bA = ((const float4*)b1)[ng], bB = ((const float4*)b1)[16 + ng];
        float accA[2][4], accB[2][4];
        #pragma unroll
        for (int mi = 0; mi < 2; ++mi) {
            accA[mi][0] = bA.x; accA[mi][1] = bA.y; accA[mi][2] = bA.z; accA[mi][3] = bA.w;
            accB[mi][0] = bB.x; accB[mi][1] = bB.y; accB[mi][2] = bB.z; accB[mi][3] = bB.w;
        }
        for (int k = 0; k < 64; ++k) {
            float4 bvA = W14[k * 32 + ng];
            float4 bvB = W14[k * 32 + 16 + ng];
            #pragma unroll
            for (int mi = 0; mi < 2; ++mi) {
                float av = sX[(mg * 2 + mi) * 65 + k];
                accA[mi][0] += av * bvA.x; accA[mi][1] += av * bvA.y;
                accA[mi][2] += av * bvA.z; accA[mi][3] += av * bvA.w;
                accB[mi][0] += av * bvB.x; accB[mi][1] += av * bvB.y;
                accB[mi][2] += av * bvB.z; accB[mi][3] += av * bvB.w;
            }
        }
        float4 w2A = ((const float4*)W2)[ng], w2B = ((const float4*)W2)[16 + ng];
        #pragma unroll
        for (int mi = 0; mi < 2; ++mi) {
            int m = mg * 2 + mi;
            float pA0 = fmaxf(accA[mi][0], 0.f), pB0 = fmaxf(accB[mi][0], 0.f);
            float pA1 = fmaxf(accA[mi][1], 0.f), pB1 = fmaxf(accB[mi][1], 0.f);
            float pA2 = fmaxf(accA[mi][2], 0.f), pB2 = fmaxf(accB[mi][2], 0.f);
            float pA3 = fmaxf(accA[mi][3], 0.f), pB3 = fmaxf(accB[mi][3], 0.f);
            sH[m * 65 + j0 + 0] = pA0 * w2A.x + pB0 * w2B.x;
            sH[m * 65 + j0 + 1] = pA1 * w2A.y + pB1 * w2B.y;
            sH[m * 65 + j0 + 2] = pA2 * w2A.z + pB2 * w2B.z;
            sH[m * 65 + j0 + 3] = pA3 * w2A.w + pB3 * w2B.w;
        }
    }
    __syncthreads();
    // ---- phase 3: exact shfl_down tree per row, write score ----
    {
        float b2v = b2[0];
        int w = tid >> 6, lane = tid & 63;
        #pragma unroll 4
        for (int t = 0; t < 8; ++t) {
            int m = w * 8 + t;
            float p = sH[m * 65 + lane];
            float s = wave_sum64(p);
            if (lane == 0 && (m0 + m) < cc)
                score[list[mbase + m0 + m]] = s + b2v;
        }
    }
}

// ---------- output gather ----------
__global__ void gather_out(const float* __restrict__ score, const int* __restrict__ t_index,
                           float* __restrict__ out) {
    int i = threadIdx.x;  // 64 threads
    int b = i >> 4;
    out[i] = score[t_index[i] + b * N_NODES];
}

// ---------- launcher ----------
extern "C" void kernel_launch(void* const* d_in, const int* in_sizes, int n_in,
                              void* d_out, int out_size, void* d_ws, size_t ws_size,
                              hipStream_t stream) {
    const int*   h_index       = (const int*)d_in[0];
    const int*   r_index       = (const int*)d_in[1];
    const int*   t_index       = (const int*)d_in[2];
    const float* hidden_states = (const float*)d_in[3];
    const int*   edge_index    = (const int*)d_in[5];
    const int*   edge_attr     = (const int*)d_in[6];
    const float* text          = (const float*)d_in[7];
    const float* rel_table     = (const float*)d_in[9];
    const float* W_lin         = (const float*)d_in[10];
    const float* b_lin         = (const float*)d_in[11];
    const float* W1            = (const float*)d_in[12];
    const float* b1            = (const float*)d_in[13];
    const float* W2            = (const float*)d_in[14];
    const float* b2            = (const float*)d_in[15];
    const float* rel_w         = (const float*)d_in[16];
    const float* conv_W        = (const float*)d_in[17];
    const float* conv_b        = (const float*)d_in[18];

    // choose full (unchunked) path if scratch allows
    auto layout_bytes = [](size_t fch) -> size_t {
        auto al = [](size_t x) { return (x + 255) & ~(size_t)255; };
        size_t o = 0;
        o += al(256) * 3;                      // scalars, state, countp
        o += al(1024) * 2;                     // ghn, ghw
        o += al((size_t)NT * 4);               // score
        o += al((size_t)N_NODES * 4);          // degb
        o += al(256);                          // qh
        o += al((size_t)NT * 4);               // sigp
        o += al((size_t)NT * 64 * 4);          // hidden
        o += al(fch * 256 * 4);                // feat
        o += al(fch * 2 * 4);                  // ampatt
        o += al((size_t)NT * 4);               // list
        o += al((size_t)(N_NODES + 1) * 4);    // rowptr
        o += al((size_t)N_NODES * 4);          // cursor
        o += al((size_t)2 * E_EDGES * 4);      // inedge
        return o;
    };
    const size_t FCH = (layout_bytes(NT) <= ws_size) ? (size_t)NT : (size_t)CHUNK;
    const int NCH = (FCH == (size_t)NT) ? 1 : 3;

    char* ws = (char*)d_ws;
    size_t off = 0;
    auto carve = [&](size_t bytes) -> char* {
        char* p = ws + off;
        off = (off + bytes + 255) & ~(size_t)255;
        return p;
    };
    // ---- zero-initialized group (contiguous; single memset) ----
    float*    scalars = (float*)carve(256);                 // [0]=thr [1]=THR [3]=pna_mean
    unsigned* state   = (unsigned*)carve(256);              // [0..3]=radix [8]=arrive [9]=release
    unsigned* countp  = (unsigned*)carve(256);
    unsigned* ghn     = (unsigned*)carve(1024);
    unsigned* ghw     = (unsigned*)carve(1024);
    float*    score   = (float*)carve((size_t)NT * 4);
    unsigned* degb    = (unsigned*)carve((size_t)N_NODES * 4);
    size_t zero_end = off;
    // ---- rest ----
    float*    qh      = (float*)carve(256);
    float*    sigp    = (float*)carve((size_t)NT * 4);
    float*    hidden  = (float*)carve((size_t)NT * 64 * 4);
    float*    feat    = (float*)carve(FCH * 256 * 4);
    float*    ampatt  = (float*)carve(FCH * 2 * 4);
    int*      list    = (int*)carve((size_t)NT * 4);
    unsigned* rowptr  = (unsigned*)carve((size_t)(N_NODES + 1) * 4);
    unsigned* cursor  = (unsigned*)carve((size_t)N_NODES * 4);
    unsigned* inedge  = (unsigned*)carve((size_t)2 * E_EDGES * 4);
    if (off > ws_size) return;

    hipMemsetAsync(ws, 0, zero_end, stream);

    count_deg<<<(E_EDGES + 255) / 256, 256, 0, stream>>>(edge_index, degb);
    scan_degrees<<<1, 1024, 0, stream>>>(degb, rowptr, cursor);
    scatter_edges<<<(E_EDGES + 255) / 256, 256, 0, stream>>>(edge_index, edge_attr, cursor, inedge);
    pna_kernel<<<1, 1024, 0, stream>>>(degb, scalars);
    init_hidden<<<(NT * 64 + 255) / 256, 256, 0, stream>>>(text, hidden);
    init_heads<<<1, 256, 0, stream>>>(h_index, r_index, hidden_states, rel_table,
                                      W_lin, b_lin, W1, b1, W2, b2, hidden, score, qh);

    const int climit  = (int)FCH;
    const int aggGrid = climit / 4;
    const int updGrid = climit / 32;
    for (int l = 0; l < 3; ++l) {
        select_compact<<<SEL_BLOCKS, 256, 0, stream>>>(score, degb, ghn, ghw, state,
                                                       scalars, countp, list, sigp, l * 4);
        for (int c = 0; c < NCH; ++c) {
            int mbase = c * climit;
            agg_feat<<<aggGrid, 256, 0, stream>>>(sigp, hidden, rowptr, inedge, rel_w,
                                                  scalars, countp, list, feat, ampatt,
                                                  l, mbase, climit);
            update_score<<<updGrid, 256, 0, stream>>>(conv_W, conv_b, countp, feat, ampatt,
                                                      hidden, score, list, W_lin, qh,
                                                      W1, b1, W2, b2, l, mbase, climit);
        }
    }
    gather_out<<<1, 64, 0, stream>>>(score, t_index, (float*)d_out);
}